// Round 5
// baseline (324.279 us; speedup 1.0000x reference)
//
#include <hip/hip_runtime.h>
#include <math.h>

#define NE 8      // experts
#define ND 512    // features
#define NH 2048   // hidden
#define NT 2048   // tokens = B*S

typedef __attribute__((ext_vector_type(8))) short short8;   // 8 bf16 = 4 VGPRs
typedef __attribute__((ext_vector_type(4))) float f32x4;    // MFMA accumulator

#define GLL(g, d) __builtin_amdgcn_global_load_lds( \
    (const __attribute__((address_space(1))) void*)(g), \
    (__attribute__((address_space(3))) void*)(d), 16, 0, 0)

// s_waitcnt imm (gfx9): vmcnt[3:0]|[15:14], expcnt[6:4], lgkmcnt[11:8]
#define WAITCNT_VM4  0x0F74   // vmcnt=4, lgkm/exp no-wait
#define WAITCNT_VM0  0x0F70   // vmcnt=0, lgkm/exp no-wait

__device__ __forceinline__ unsigned short f2bf(float x) {
    unsigned int u = __builtin_bit_cast(unsigned int, x);
    u += 0x7FFFu + ((u >> 16) & 1u);            // round-to-nearest-even
    return (unsigned short)(u >> 16);
}

__device__ __forceinline__ short8 neg8(short8 v) {
    int4 u = __builtin_bit_cast(int4, v);
    u.x ^= 0x80008000; u.y ^= 0x80008000; u.z ^= 0x80008000; u.w ^= 0x80008000;
    return __builtin_bit_cast(short8, u);
}

__device__ __forceinline__ short8 lds8(const unsigned short* p) {
    return *(const short8*)p;
}

// ---------------- gating (fp32, exact argmax semantics) ----------------
__global__ __launch_bounds__(256) void gate_kernel(
    const float* __restrict__ xr, const float* __restrict__ xi,
    const float* __restrict__ gW, const float* __restrict__ gb,
    float* __restrict__ gate_w,
    int* __restrict__ counts, int* __restrict__ tok_list)
{
    int t = blockIdx.x;
    int tid = threadIdx.x;
    const float* xrt = xr + (size_t)t * ND;
    const float* xit = xi + (size_t)t * ND;

    float acc[NE] = {0,0,0,0,0,0,0,0};
    for (int r = tid; r < 2 * ND; r += 256) {
        int d = r & (ND - 1);
        float a = xrt[d], b = xit[d];
        float v = (r < ND) ? sqrtf(a * a + b * b) : atan2f(b, a);
        const float4* g = (const float4*)(gW + (size_t)r * NE);
        float4 g0 = g[0], g1 = g[1];
        acc[0] += v * g0.x; acc[1] += v * g0.y; acc[2] += v * g0.z; acc[3] += v * g0.w;
        acc[4] += v * g1.x; acc[5] += v * g1.y; acc[6] += v * g1.z; acc[7] += v * g1.w;
    }
    #pragma unroll
    for (int e = 0; e < NE; e++) {
        for (int off = 32; off > 0; off >>= 1)
            acc[e] += __shfl_down(acc[e], off, 64);
    }
    __shared__ float part[4][NE];
    int wave = tid >> 6, lane = tid & 63;
    if (lane == 0) {
        #pragma unroll
        for (int e = 0; e < NE; e++) part[wave][e] = acc[e];
    }
    __syncthreads();
    if (tid == 0) {
        float s[NE];
        #pragma unroll
        for (int e = 0; e < NE; e++)
            s[e] = part[0][e] + part[1][e] + part[2][e] + part[3][e] + gb[e];
        int amax = 0; float m = s[0];
        #pragma unroll
        for (int e = 1; e < NE; e++) if (s[e] > m) { m = s[e]; amax = e; }
        float denom = 0.f;
        #pragma unroll
        for (int e = 0; e < NE; e++) denom += expf(s[e] - m);
        gate_w[t] = 1.0f / denom;
        int pos = atomicAdd(&counts[amax], 1);
        tok_list[amax * NT + pos] = t;
    }
}

// ---------------- x -> bf16 ----------------
__global__ __launch_bounds__(256) void convx_kernel(
    const float* __restrict__ xr, const float* __restrict__ xi,
    unsigned short* __restrict__ obr, unsigned short* __restrict__ obi)
{
    int i = blockIdx.x * 256 + threadIdx.x;
    float4 vr = ((const float4*)xr)[i];
    float4 vi = ((const float4*)xi)[i];
    ((ushort4*)obr)[i] = make_ushort4(f2bf(vr.x), f2bf(vr.y), f2bf(vr.z), f2bf(vr.w));
    ((ushort4*)obi)[i] = make_ushort4(f2bf(vi.x), f2bf(vi.y), f2bf(vi.z), f2bf(vi.w));
}

// ---------------- weight transpose + bf16: src fp32 [e][R][C] -> dst bf16 [e][C][R] ----
__global__ __launch_bounds__(256) void transw_kernel(
    const float* __restrict__ s0, unsigned short* __restrict__ d0,
    const float* __restrict__ s1, unsigned short* __restrict__ d1,
    int R, int C)
{
    __shared__ float tile[64][65];
    int e = blockIdx.z;
    int c0 = blockIdx.x * 64, r0 = blockIdx.y * 64;
    size_t off = (size_t)e * R * C;
    int tid = threadIdx.x;
    #pragma unroll
    for (int p = 0; p < 2; ++p) {
        const float* src = (p ? s1 : s0) + off;
        unsigned short* dst = (p ? d1 : d0) + off;
        if (p) __syncthreads();
        for (int i = 0; i < 16; ++i) {
            int idx = tid + i * 256;
            int r = idx >> 6, c = idx & 63;
            tile[r][c] = src[(size_t)(r0 + r) * C + c0 + c];
        }
        __syncthreads();
        for (int i = 0; i < 16; ++i) {
            int idx = tid + i * 256;
            int c = idx >> 6, r = idx & 63;
            dst[(size_t)(c0 + c) * R + r0 + r] = f2bf(tile[r][c]);
        }
    }
}

// ---------------- stage 1: complex D->H, double-buffered MFMA + ModReLU -> h bf16
// block tile: 64 tokens x 64 cols, BK=32, DOUBLE-buffered GLL staging with
// fine-grained vmcnt (prefetch stays in flight across the barrier).
// LDS row = 64 B (4 x 16B chunks); chunk swizzle: phys = logical ^ ((row>>1)&3)
// -> fragment reads are 2-way bank-aliased (free, m136).
__global__ __launch_bounds__(256, 4) void moe1_kernel(
    const unsigned short* __restrict__ xbr, const unsigned short* __restrict__ xbi,
    const unsigned short* __restrict__ w1tr, const unsigned short* __restrict__ w1ti,
    const float* __restrict__ b1r, const float* __restrict__ b1i,
    const float* __restrict__ mod_b,
    const int* __restrict__ counts, const int* __restrict__ tok_list,
    unsigned short* __restrict__ hr, unsigned short* __restrict__ hi)
{
    int e = blockIdx.z;
    int n = counts[e];
    int mbase = blockIdx.y * 64;
    if (mbase >= n) return;
    int n0 = blockIdx.x * 64;
    int tid = threadIdx.x;
    int w = tid >> 6, l = tid & 63;
    int l15 = l & 15, quad = l >> 4;

    __shared__ unsigned short sAr[2][64 * 32];   // 4 KB per buffer
    __shared__ unsigned short sAi[2][64 * 32];
    __shared__ unsigned short sBr[2][64 * 32];
    __shared__ unsigned short sBi[2][64 * 32];
    __shared__ int toks[64];

    const int* tl = tok_list + e * NT;
    if (tid < 64) {
        int idx = mbase + tid;
        toks[tid] = tl[idx < n ? idx : n - 1];
    }
    __syncthreads();

    // ---- staging addresses: thread -> (row, phys chunk); fetch swizzled global chunk
    int r = tid >> 2;                 // 0..63
    int pc = tid & 3;                 // physical 16B chunk in row
    int gc = pc ^ ((r >> 1) & 3);     // global (logical) chunk fetched into pc
    int tokA = toks[r];
    const unsigned short* gAr = xbr + (size_t)tokA * ND + gc * 8;
    const unsigned short* gAi = xbi + (size_t)tokA * ND + gc * 8;
    size_t browB = (size_t)e * NH + n0 + r;
    const unsigned short* gBr = w1tr + browB * ND + gc * 8;
    const unsigned short* gBi = w1ti + browB * ND + gc * 8;
    int woff = w * 512;               // wave's 16 rows x 32 elems

    // ---- fragment read offsets (unswizzle): perm same for all row-groups
    int perm8 = ((quad ^ (l15 >> 1)) & 3) * 8;
    int browF = (w * 16 + l15) * 32 + perm8;     // B frag row offset
    int arow0 = l15 * 32 + perm8;                // A frag row offset (m=0)

    f32x4 accr[4] = {}, acci[4] = {};

    // prologue: tile 0 -> buf 0
    GLL(gAr, &sAr[0][woff]); GLL(gAi, &sAi[0][woff]);
    GLL(gBr, &sBr[0][woff]); GLL(gBi, &sBi[0][woff]);

    int cur = 0;
    const int NKT = ND / 32;          // 16
    #pragma unroll 2
    for (int kt = 0; kt < NKT - 1; ++kt) {
        int nxt = cur ^ 1;
        int ko = (kt + 1) * 32;
        GLL(gAr + ko, &sAr[nxt][woff]); GLL(gAi + ko, &sAi[nxt][woff]);
        GLL(gBr + ko, &sBr[nxt][woff]); GLL(gBi + ko, &sBi[nxt][woff]);
        __builtin_amdgcn_s_waitcnt(WAITCNT_VM4);   // wait only PREVIOUS tile's 4
        __builtin_amdgcn_s_barrier();
        __builtin_amdgcn_sched_barrier(0);
        {
            short8 br  = lds8(&sBr[cur][browF]);
            short8 bi2 = lds8(&sBi[cur][browF]);
            #pragma unroll
            for (int m = 0; m < 4; ++m) {
                short8 ar  = lds8(&sAr[cur][arow0 + m * 512]);
                short8 ai2 = lds8(&sAi[cur][arow0 + m * 512]);
                short8 an  = neg8(ai2);
                accr[m] = __builtin_amdgcn_mfma_f32_16x16x32_bf16(ar,  br,  accr[m], 0, 0, 0);
                accr[m] = __builtin_amdgcn_mfma_f32_16x16x32_bf16(an,  bi2, accr[m], 0, 0, 0);
                acci[m] = __builtin_amdgcn_mfma_f32_16x16x32_bf16(ar,  bi2, acci[m], 0, 0, 0);
                acci[m] = __builtin_amdgcn_mfma_f32_16x16x32_bf16(ai2, br,  acci[m], 0, 0, 0);
            }
        }
        __builtin_amdgcn_sched_barrier(0);
        __builtin_amdgcn_s_barrier();
        cur = nxt;
    }
    __builtin_amdgcn_s_waitcnt(WAITCNT_VM0);
    __builtin_amdgcn_s_barrier();
    __builtin_amdgcn_sched_barrier(0);
    {
        short8 br  = lds8(&sBr[cur][browF]);
        short8 bi2 = lds8(&sBi[cur][browF]);
        #pragma unroll
        for (int m = 0; m < 4; ++m) {
            short8 ar  = lds8(&sAr[cur][arow0 + m * 512]);
            short8 ai2 = lds8(&sAi[cur][arow0 + m * 512]);
            short8 an  = neg8(ai2);
            accr[m] = __builtin_amdgcn_mfma_f32_16x16x32_bf16(ar,  br,  accr[m], 0, 0, 0);
            accr[m] = __builtin_amdgcn_mfma_f32_16x16x32_bf16(an,  bi2, accr[m], 0, 0, 0);
            acci[m] = __builtin_amdgcn_mfma_f32_16x16x32_bf16(ar,  bi2, acci[m], 0, 0, 0);
            acci[m] = __builtin_amdgcn_mfma_f32_16x16x32_bf16(ai2, br,  acci[m], 0, 0, 0);
        }
    }

    // epilogue: C/D layout col = lane&15 (N), row = quad*4 + r (M)
    int col = n0 + w * 16 + l15;
    float bre = b1r[(size_t)e * NH + col];
    float bie = b1i[(size_t)e * NH + col];
    float mbv = mod_b[(size_t)e * NH + col];
    #pragma unroll
    for (int m = 0; m < 4; ++m) {
        #pragma unroll
        for (int rr = 0; rr < 4; ++rr) {
            int tix = m * 16 + quad * 4 + rr;
            if (mbase + tix >= n) continue;
            int tok = toks[tix];
            float vr = accr[m][rr] + bre;
            float vi = acci[m][rr] + bie;
            float a = sqrtf(vr * vr + vi * vi + 1e-10f);
            float sc = fmaxf(a + mbv, 0.0f) / (a + 1e-10f);
            hr[(size_t)tok * NH + col] = f2bf(vr * sc);
            hi[(size_t)tok * NH + col] = f2bf(vi * sc);
        }
    }
}

// ---------------- stage 2: complex H->D, split-K=4, double-buffered -> atomic out
__global__ __launch_bounds__(256, 4) void moe2_kernel(
    const unsigned short* __restrict__ hr, const unsigned short* __restrict__ hi,
    const unsigned short* __restrict__ w2tr, const unsigned short* __restrict__ w2ti,
    const float* __restrict__ b2r, const float* __restrict__ b2i,
    const int* __restrict__ counts, const int* __restrict__ tok_list,
    const float* __restrict__ gate_w,
    float* __restrict__ out)
{
    int e = blockIdx.z >> 2;
    int ksl = blockIdx.z & 3;
    int n = counts[e];
    int mbase = blockIdx.y * 64;
    if (mbase >= n) return;
    int n0 = blockIdx.x * 64;
    int kbase = ksl * (NH / 4);
    int tid = threadIdx.x;
    int w = tid >> 6, l = tid & 63;
    int l15 = l & 15, quad = l >> 4;

    __shared__ unsigned short sAr[2][64 * 32];
    __shared__ unsigned short sAi[2][64 * 32];
    __shared__ unsigned short sBr[2][64 * 32];
    __shared__ unsigned short sBi[2][64 * 32];
    __shared__ int toks[64];

    const int* tl = tok_list + e * NT;
    if (tid < 64) {
        int idx = mbase + tid;
        toks[tid] = tl[idx < n ? idx : n - 1];
    }
    __syncthreads();

    int r = tid >> 2;
    int pc = tid & 3;
    int gc = pc ^ ((r >> 1) & 3);
    int tokA = toks[r];
    const unsigned short* gAr = hr + (size_t)tokA * NH + kbase + gc * 8;
    const unsigned short* gAi = hi + (size_t)tokA * NH + kbase + gc * 8;
    size_t browB = (size_t)e * ND + n0 + r;
    const unsigned short* gBr = w2tr + browB * NH + kbase + gc * 8;
    const unsigned short* gBi = w2ti + browB * NH + kbase + gc * 8;
    int woff = w * 512;

    int perm8 = ((quad ^ (l15 >> 1)) & 3) * 8;
    int browF = (w * 16 + l15) * 32 + perm8;
    int arow0 = l15 * 32 + perm8;

    f32x4 accr[4] = {}, acci[4] = {};

    GLL(gAr, &sAr[0][woff]); GLL(gAi, &sAi[0][woff]);
    GLL(gBr, &sBr[0][woff]); GLL(gBi, &sBi[0][woff]);

    int cur = 0;
    const int NKT = (NH / 4) / 32;    // 16
    #pragma unroll 2
    for (int kt = 0; kt < NKT - 1; ++kt) {
        int nxt = cur ^ 1;
        int ko = (kt + 1) * 32;
        GLL(gAr + ko, &sAr[nxt][woff]); GLL(gAi + ko, &sAi[nxt][woff]);
        GLL(gBr + ko, &sBr[nxt][woff]); GLL(gBi + ko, &sBi[nxt][woff]);
        __builtin_amdgcn_s_waitcnt(WAITCNT_VM4);
        __builtin_amdgcn_s_barrier();
        __builtin_amdgcn_sched_barrier(0);
        {
            short8 br  = lds8(&sBr[cur][browF]);
            short8 bi2 = lds8(&sBi[cur][browF]);
            #pragma unroll
            for (int m = 0; m < 4; ++m) {
                short8 ar  = lds8(&sAr[cur][arow0 + m * 512]);
                short8 ai2 = lds8(&sAi[cur][arow0 + m * 512]);
                short8 an  = neg8(ai2);
                accr[m] = __builtin_amdgcn_mfma_f32_16x16x32_bf16(ar,  br,  accr[m], 0, 0, 0);
                accr[m] = __builtin_amdgcn_mfma_f32_16x16x32_bf16(an,  bi2, accr[m], 0, 0, 0);
                acci[m] = __builtin_amdgcn_mfma_f32_16x16x32_bf16(ar,  bi2, acci[m], 0, 0, 0);
                acci[m] = __builtin_amdgcn_mfma_f32_16x16x32_bf16(ai2, br,  acci[m], 0, 0, 0);
            }
        }
        __builtin_amdgcn_sched_barrier(0);
        __builtin_amdgcn_s_barrier();
        cur = nxt;
    }
    __builtin_amdgcn_s_waitcnt(WAITCNT_VM0);
    __builtin_amdgcn_s_barrier();
    __builtin_amdgcn_sched_barrier(0);
    {
        short8 br  = lds8(&sBr[cur][browF]);
        short8 bi2 = lds8(&sBi[cur][browF]);
        #pragma unroll
        for (int m = 0; m < 4; ++m) {
            short8 ar  = lds8(&sAr[cur][arow0 + m * 512]);
            short8 ai2 = lds8(&sAi[cur][arow0 + m * 512]);
            short8 an  = neg8(ai2);
            accr[m] = __builtin_amdgcn_mfma_f32_16x16x32_bf16(ar,  br,  accr[m], 0, 0, 0);
            accr[m] = __builtin_amdgcn_mfma_f32_16x16x32_bf16(an,  bi2, accr[m], 0, 0, 0);
            acci[m] = __builtin_amdgcn_mfma_f32_16x16x32_bf16(ar,  bi2, acci[m], 0, 0, 0);
            acci[m] = __builtin_amdgcn_mfma_f32_16x16x32_bf16(ai2, br,  acci[m], 0, 0, 0);
        }
    }

    int col = n0 + w * 16 + l15;
    float bre = (ksl == 0) ? b2r[(size_t)e * ND + col] : 0.0f;
    float bie = (ksl == 0) ? b2i[(size_t)e * ND + col] : 0.0f;
    #pragma unroll
    for (int m = 0; m < 4; ++m) {
        #pragma unroll
        for (int rr = 0; rr < 4; ++rr) {
            int tix = m * 16 + quad * 4 + rr;
            if (mbase + tix >= n) continue;
            int tok = toks[tix];
            float gw = gate_w[tok];
            atomicAdd(&out[(size_t)tok * ND + col], (accr[m][rr] + bre) * gw);
            atomicAdd(&out[(size_t)NT * ND + (size_t)tok * ND + col], (acci[m][rr] + bie) * gw);
        }
    }
}

extern "C" void kernel_launch(void* const* d_in, const int* in_sizes, int n_in,
                              void* d_out, int out_size, void* d_ws, size_t ws_size,
                              hipStream_t stream) {
    const float* xr   = (const float*)d_in[0];
    const float* xi   = (const float*)d_in[1];
    const float* gW   = (const float*)d_in[2];
    const float* gb   = (const float*)d_in[3];
    const float* W1r  = (const float*)d_in[4];
    const float* W1i  = (const float*)d_in[5];
    const float* b1r  = (const float*)d_in[6];
    const float* b1i  = (const float*)d_in[7];
    const float* modb = (const float*)d_in[8];
    const float* W2r  = (const float*)d_in[9];
    const float* W2i  = (const float*)d_in[10];
    const float* b2r  = (const float*)d_in[11];
    const float* b2i  = (const float*)d_in[12];
    float* out = (float*)d_out;

    char* ws = (char*)d_ws;
    int*   counts   = (int*)ws;                              // 256 B
    float* gate_w   = (float*)(ws + 256);                    // NT*4
    int*   tok_list = (int*)(ws + 256 + 8192);               // NE*NT*4
    size_t off = 256 + 8192 + (size_t)NE * NT * 4;
    unsigned short* xbr  = (unsigned short*)(ws + off); off += (size_t)NT * ND * 2;
    unsigned short* xbi  = (unsigned short*)(ws + off); off += (size_t)NT * ND * 2;
    unsigned short* w1tr = (unsigned short*)(ws + off); off += (size_t)NE * ND * NH * 2;
    unsigned short* w1ti = (unsigned short*)(ws + off); off += (size_t)NE * ND * NH * 2;
    unsigned short* w2tr = (unsigned short*)(ws + off); off += (size_t)NE * ND * NH * 2;
    unsigned short* w2ti = (unsigned short*)(ws + off); off += (size_t)NE * ND * NH * 2;
    unsigned short* h_r  = (unsigned short*)(ws + off); off += (size_t)NT * NH * 2;
    unsigned short* h_i  = (unsigned short*)(ws + off); off += (size_t)NT * NH * 2;

    hipMemsetAsync(counts, 0, 64 * sizeof(int), stream);
    hipMemsetAsync(out, 0, (size_t)out_size * sizeof(float), stream);
    gate_kernel<<<NT, 256, 0, stream>>>(xr, xi, gW, gb, gate_w, counts, tok_list);
    convx_kernel<<<(NT * ND / 4) / 256, 256, 0, stream>>>(xr, xi, xbr, xbi);
    transw_kernel<<<dim3(NH / 64, ND / 64, NE), 256, 0, stream>>>(W1r, w1tr, W1i, w1ti, ND, NH);
    transw_kernel<<<dim3(ND / 64, NH / 64, NE), 256, 0, stream>>>(W2r, w2tr, W2i, w2ti, NH, ND);
    moe1_kernel<<<dim3(NH / 64, NT / 64, NE), 256, 0, stream>>>(
        xbr, xbi, w1tr, w1ti, b1r, b1i, modb, counts, tok_list, h_r, h_i);
    moe2_kernel<<<dim3(ND / 64, NT / 64, NE * 4), 256, 0, stream>>>(
        h_r, h_i, w2tr, w2ti, b2r, b2i, counts, tok_list, gate_w, out);
}

// Round 6
// 318.247 us; speedup vs baseline: 1.0190x; 1.0190x over previous
//
#include <hip/hip_runtime.h>
#include <math.h>

#define NE 8      // experts
#define ND 512    // features
#define NH 2048   // hidden
#define NT 2048   // tokens = B*S

typedef __attribute__((ext_vector_type(8)))  short short8;   // 8 bf16 = 4 VGPRs
typedef __attribute__((ext_vector_type(16))) float f32x16;   // 32x32 MFMA accumulator

#define GLL(g, d) __builtin_amdgcn_global_load_lds( \
    (const __attribute__((address_space(1))) void*)(g), \
    (__attribute__((address_space(3))) void*)(d), 16, 0, 0)

__device__ __forceinline__ unsigned short f2bf(float x) {
    unsigned int u = __builtin_bit_cast(unsigned int, x);
    u += 0x7FFFu + ((u >> 16) & 1u);            // round-to-nearest-even
    return (unsigned short)(u >> 16);
}

__device__ __forceinline__ short8 neg8(short8 v) {
    int4 u = __builtin_bit_cast(int4, v);
    u.x ^= 0x80008000; u.y ^= 0x80008000; u.z ^= 0x80008000; u.w ^= 0x80008000;
    return __builtin_bit_cast(short8, u);
}

__device__ __forceinline__ short8 lds8(const unsigned short* p) {
    return *(const short8*)p;
}

// ---------------- gating (fp32, exact argmax) + fused x->bf16 ----------------
__global__ __launch_bounds__(256) void gate_kernel(
    const float* __restrict__ xr, const float* __restrict__ xi,
    const float* __restrict__ gW, const float* __restrict__ gb,
    float* __restrict__ gate_w,
    int* __restrict__ counts, int* __restrict__ tok_list,
    unsigned short* __restrict__ xbr, unsigned short* __restrict__ xbi)
{
    int t = blockIdx.x;
    int tid = threadIdx.x;
    const float* xrt = xr + (size_t)t * ND;
    const float* xit = xi + (size_t)t * ND;
    unsigned short* obr = xbr + (size_t)t * ND;
    unsigned short* obi = xbi + (size_t)t * ND;

    float acc[NE] = {0,0,0,0,0,0,0,0};
    for (int r = tid; r < 2 * ND; r += 256) {
        int d = r & (ND - 1);
        float a = xrt[d], b = xit[d];
        float v;
        if (r < ND) {
            v = sqrtf(a * a + b * b);
            obr[d] = f2bf(a);            // fused convx
            obi[d] = f2bf(b);
        } else {
            v = atan2f(b, a);
        }
        const float4* g = (const float4*)(gW + (size_t)r * NE);
        float4 g0 = g[0], g1 = g[1];
        acc[0] += v * g0.x; acc[1] += v * g0.y; acc[2] += v * g0.z; acc[3] += v * g0.w;
        acc[4] += v * g1.x; acc[5] += v * g1.y; acc[6] += v * g1.z; acc[7] += v * g1.w;
    }
    #pragma unroll
    for (int e = 0; e < NE; e++) {
        for (int off = 32; off > 0; off >>= 1)
            acc[e] += __shfl_down(acc[e], off, 64);
    }
    __shared__ float part[4][NE];
    int wave = tid >> 6, lane = tid & 63;
    if (lane == 0) {
        #pragma unroll
        for (int e = 0; e < NE; e++) part[wave][e] = acc[e];
    }
    __syncthreads();
    if (tid == 0) {
        float s[NE];
        #pragma unroll
        for (int e = 0; e < NE; e++)
            s[e] = part[0][e] + part[1][e] + part[2][e] + part[3][e] + gb[e];
        int amax = 0; float m = s[0];
        #pragma unroll
        for (int e = 1; e < NE; e++) if (s[e] > m) { m = s[e]; amax = e; }
        float denom = 0.f;
        #pragma unroll
        for (int e = 0; e < NE; e++) denom += expf(s[e] - m);
        gate_w[t] = 1.0f / denom;
        int pos = atomicAdd(&counts[amax], 1);
        tok_list[amax * NT + pos] = t;
    }
}

// ---- weight transpose + bf16 (vectorized): fp32 [e][R][C] -> bf16 [e][C][R] ----
__global__ __launch_bounds__(256) void transw_kernel(
    const float* __restrict__ s0, unsigned short* __restrict__ d0,
    const float* __restrict__ s1, unsigned short* __restrict__ d1,
    int R, int C)
{
    __shared__ unsigned int tile[64 * 33];   // packed bf16 pairs, +1 uint pad
    int e = blockIdx.z;
    int c0 = blockIdx.x * 64, r0 = blockIdx.y * 64;
    size_t off = (size_t)e * R * C;
    int tid = threadIdx.x;
    int rl = tid >> 4;                // 0..15
    int c4 = (tid & 15) * 4;          // 0..60
    int r4 = (tid & 15) * 4;
    #pragma unroll
    for (int p = 0; p < 2; ++p) {
        const float* src = (p ? s1 : s0) + off;
        unsigned short* dst = (p ? d1 : d0) + off;
        if (p) __syncthreads();
        #pragma unroll
        for (int jj = 0; jj < 4; ++jj) {
            int r = rl + 16 * jj;
            float4 v = *(const float4*)(src + (size_t)(r0 + r) * C + c0 + c4);
            tile[r * 33 + (c4 >> 1)]     = ((unsigned)f2bf(v.y) << 16) | f2bf(v.x);
            tile[r * 33 + (c4 >> 1) + 1] = ((unsigned)f2bf(v.w) << 16) | f2bf(v.z);
        }
        __syncthreads();
        #pragma unroll
        for (int ii = 0; ii < 4; ++ii) {
            int c = (tid >> 4) + 16 * ii;
            unsigned short o[4];
            #pragma unroll
            for (int j = 0; j < 4; ++j) {
                unsigned int u = tile[(r4 + j) * 33 + (c >> 1)];
                o[j] = (c & 1) ? (unsigned short)(u >> 16) : (unsigned short)(u & 0xFFFF);
            }
            *(ushort4*)(dst + (size_t)(c0 + c) * R + r0 + r4) = make_ushort4(o[0], o[1], o[2], o[3]);
        }
        if (p == 0) __syncthreads();
    }
}

// ---------------- stage 1: complex D->H, 32x32x16 MFMA + ModReLU -> h bf16 ----
// block tile 64M x 128N, BK=64; 4 waves as 2Mx2N, wave tile 32M x 64N.
// LDS rows = 128 B (8 chunks); swizzle gc = c ^ (row&7) -> conflict-free b128.
__global__ __launch_bounds__(256, 3) void moe1_kernel(
    const unsigned short* __restrict__ xbr, const unsigned short* __restrict__ xbi,
    const unsigned short* __restrict__ w1tr, const unsigned short* __restrict__ w1ti,
    const float* __restrict__ b1r, const float* __restrict__ b1i,
    const float* __restrict__ mod_b,
    const int* __restrict__ counts, const int* __restrict__ tok_list,
    unsigned short* __restrict__ hr, unsigned short* __restrict__ hi)
{
    int e = blockIdx.z;
    int n = counts[e];
    int mbase = blockIdx.y * 64;
    if (mbase >= n) return;
    int n0 = blockIdx.x * 128;
    int tid = threadIdx.x;
    int w = tid >> 6, l = tid & 63;
    int l31 = l & 31, half = l >> 5;
    int mw = w & 1, nw = w >> 1;

    __shared__ unsigned short sAr[64 * 64];    // 8 KB
    __shared__ unsigned short sAi[64 * 64];
    __shared__ unsigned short sBr[128 * 64];   // 16 KB
    __shared__ unsigned short sBi[128 * 64];
    __shared__ int toks[64];

    const int* tl = tok_list + e * NT;
    if (tid < 64) {
        int idx = mbase + tid;
        toks[tid] = tl[idx < n ? idx : n - 1];
    }
    __syncthreads();

    // staging: thread -> (row rloc(+32j), chunk c8); global chunk swizzled
    int c8 = tid & 7;
    int rloc = tid >> 3;                  // 0..31
    int gc8 = (c8 ^ (rloc & 7)) * 8;      // element offset (16B units *8)
    int tA0 = toks[rloc], tA1 = toks[rloc + 32];
    const unsigned short* gAr0 = xbr + (size_t)tA0 * ND + gc8;
    const unsigned short* gAi0 = xbi + (size_t)tA0 * ND + gc8;
    const unsigned short* gAr1 = xbr + (size_t)tA1 * ND + gc8;
    const unsigned short* gAi1 = xbi + (size_t)tA1 * ND + gc8;
    size_t brow = (size_t)e * NH + n0 + rloc;
    const unsigned short* gBr0 = w1tr + (brow +  0) * ND + gc8;
    const unsigned short* gBr1 = w1tr + (brow + 32) * ND + gc8;
    const unsigned short* gBr2 = w1tr + (brow + 64) * ND + gc8;
    const unsigned short* gBr3 = w1tr + (brow + 96) * ND + gc8;
    const unsigned short* gBi0 = w1ti + (brow +  0) * ND + gc8;
    const unsigned short* gBi1 = w1ti + (brow + 32) * ND + gc8;
    const unsigned short* gBi2 = w1ti + (brow + 64) * ND + gc8;
    const unsigned short* gBi3 = w1ti + (brow + 96) * ND + gc8;

    int dA = rloc * 64 + c8 * 8;
    unsigned short* dAr0 = sAr + dA;          unsigned short* dAr1 = sAr + dA + 32 * 64;
    unsigned short* dAi0 = sAi + dA;          unsigned short* dAi1 = sAi + dA + 32 * 64;
    unsigned short* dBr0 = sBr + dA;          unsigned short* dBr1 = sBr + dA + 32 * 64;
    unsigned short* dBr2 = sBr + dA + 64*64;  unsigned short* dBr3 = sBr + dA + 96 * 64;
    unsigned short* dBi0 = sBi + dA;          unsigned short* dBi1 = sBi + dA + 32 * 64;
    unsigned short* dBi2 = sBi + dA + 64*64;  unsigned short* dBi3 = sBi + dA + 96 * 64;

    f32x16 accr[2] = {}, acci[2] = {};
    int am = mw * 32 + l31;
    int aoffBase = am * 64;
    int bn0 = nw * 64 + l31;
    int bn1 = nw * 64 + 32 + l31;

    for (int kt = 0; kt < ND / 64; ++kt) {
        __syncthreads();
        int ko = kt * 64;
        GLL(gAr0 + ko, dAr0); GLL(gAr1 + ko, dAr1);
        GLL(gAi0 + ko, dAi0); GLL(gAi1 + ko, dAi1);
        GLL(gBr0 + ko, dBr0); GLL(gBr1 + ko, dBr1);
        GLL(gBr2 + ko, dBr2); GLL(gBr3 + ko, dBr3);
        GLL(gBi0 + ko, dBi0); GLL(gBi1 + ko, dBi1);
        GLL(gBi2 + ko, dBi2); GLL(gBi3 + ko, dBi3);
        __syncthreads();
        #pragma unroll
        for (int ks = 0; ks < 4; ++ks) {
            int kc = ks * 2 + half;
            int ao = aoffBase + ((kc ^ (am & 7)) * 8);
            short8 ar = lds8(sAr + ao);
            short8 ai = lds8(sAi + ao);
            short8 an = neg8(ai);
            int bo0 = bn0 * 64 + ((kc ^ (bn0 & 7)) * 8);
            int bo1 = bn1 * 64 + ((kc ^ (bn1 & 7)) * 8);
            short8 br0 = lds8(sBr + bo0), bi0 = lds8(sBi + bo0);
            short8 br1 = lds8(sBr + bo1), bi1 = lds8(sBi + bo1);
            accr[0] = __builtin_amdgcn_mfma_f32_32x32x16_bf16(ar, br0, accr[0], 0, 0, 0);
            accr[0] = __builtin_amdgcn_mfma_f32_32x32x16_bf16(an, bi0, accr[0], 0, 0, 0);
            acci[0] = __builtin_amdgcn_mfma_f32_32x32x16_bf16(ar, bi0, acci[0], 0, 0, 0);
            acci[0] = __builtin_amdgcn_mfma_f32_32x32x16_bf16(ai, br0, acci[0], 0, 0, 0);
            accr[1] = __builtin_amdgcn_mfma_f32_32x32x16_bf16(ar, br1, accr[1], 0, 0, 0);
            accr[1] = __builtin_amdgcn_mfma_f32_32x32x16_bf16(an, bi1, accr[1], 0, 0, 0);
            acci[1] = __builtin_amdgcn_mfma_f32_32x32x16_bf16(ar, bi1, acci[1], 0, 0, 0);
            acci[1] = __builtin_amdgcn_mfma_f32_32x32x16_bf16(ai, br1, acci[1], 0, 0, 0);
        }
    }

    // epilogue: 32x32 C/D: col = lane&31, row = (reg&3) + 8*(reg>>2) + 4*(lane>>5)
    #pragma unroll
    for (int ns = 0; ns < 2; ++ns) {
        int col = n0 + nw * 64 + ns * 32 + l31;
        float bre = b1r[(size_t)e * NH + col];
        float bie = b1i[(size_t)e * NH + col];
        float mbv = mod_b[(size_t)e * NH + col];
        #pragma unroll
        for (int reg = 0; reg < 16; ++reg) {
            int row = (reg & 3) + 8 * (reg >> 2) + 4 * half;
            int tix = mw * 32 + row;
            if (mbase + tix >= n) continue;
            int tok = toks[tix];
            float vr = accr[ns][reg] + bre;
            float vi = acci[ns][reg] + bie;
            float a = sqrtf(vr * vr + vi * vi + 1e-10f);
            float sc = fmaxf(a + mbv, 0.0f) / (a + 1e-10f);
            hr[(size_t)tok * NH + col] = f2bf(vr * sc);
            hi[(size_t)tok * NH + col] = f2bf(vi * sc);
        }
    }
}

// ---------------- stage 2: complex H->D, split-K=4, 32x32x16 -> atomic out ----
// block tile 64M x 64N, K-slice 512, BK=64; 4 waves as 2Mx2N, wave 32M x 32N.
__global__ __launch_bounds__(256, 4) void moe2_kernel(
    const unsigned short* __restrict__ hr, const unsigned short* __restrict__ hi,
    const unsigned short* __restrict__ w2tr, const unsigned short* __restrict__ w2ti,
    const float* __restrict__ b2r, const float* __restrict__ b2i,
    const int* __restrict__ counts, const int* __restrict__ tok_list,
    const float* __restrict__ gate_w,
    float* __restrict__ out)
{
    int e = blockIdx.z >> 2;
    int ksl = blockIdx.z & 3;
    int n = counts[e];
    int mbase = blockIdx.y * 64;
    if (mbase >= n) return;
    int n0 = blockIdx.x * 64;
    int kbase = ksl * (NH / 4);
    int tid = threadIdx.x;
    int w = tid >> 6, l = tid & 63;
    int l31 = l & 31, half = l >> 5;
    int mw = w & 1, nw = w >> 1;

    __shared__ unsigned short sAr[64 * 64];
    __shared__ unsigned short sAi[64 * 64];
    __shared__ unsigned short sBr[64 * 64];
    __shared__ unsigned short sBi[64 * 64];
    __shared__ int toks[64];

    const int* tl = tok_list + e * NT;
    if (tid < 64) {
        int idx = mbase + tid;
        toks[tid] = tl[idx < n ? idx : n - 1];
    }
    __syncthreads();

    int c8 = tid & 7;
    int rloc = tid >> 3;
    int gc8 = (c8 ^ (rloc & 7)) * 8;
    int tA0 = toks[rloc], tA1 = toks[rloc + 32];
    const unsigned short* gAr0 = hr + (size_t)tA0 * NH + kbase + gc8;
    const unsigned short* gAi0 = hi + (size_t)tA0 * NH + kbase + gc8;
    const unsigned short* gAr1 = hr + (size_t)tA1 * NH + kbase + gc8;
    const unsigned short* gAi1 = hi + (size_t)tA1 * NH + kbase + gc8;
    size_t brow = (size_t)e * ND + n0 + rloc;
    const unsigned short* gBr0 = w2tr + (brow +  0) * NH + kbase + gc8;
    const unsigned short* gBr1 = w2tr + (brow + 32) * NH + kbase + gc8;
    const unsigned short* gBi0 = w2ti + (brow +  0) * NH + kbase + gc8;
    const unsigned short* gBi1 = w2ti + (brow + 32) * NH + kbase + gc8;

    int dA = rloc * 64 + c8 * 8;
    unsigned short* dAr0 = sAr + dA; unsigned short* dAr1 = sAr + dA + 32 * 64;
    unsigned short* dAi0 = sAi + dA; unsigned short* dAi1 = sAi + dA + 32 * 64;
    unsigned short* dBr0 = sBr + dA; unsigned short* dBr1 = sBr + dA + 32 * 64;
    unsigned short* dBi0 = sBi + dA; unsigned short* dBi1 = sBi + dA + 32 * 64;

    f32x16 accr = {}, acci = {};
    int am = mw * 32 + l31;
    int aoffBase = am * 64;
    int bn = nw * 32 + l31;
    int boffBase = bn * 64;

    for (int kt = 0; kt < (NH / 4) / 64; ++kt) {
        __syncthreads();
        int ko = kt * 64;
        GLL(gAr0 + ko, dAr0); GLL(gAr1 + ko, dAr1);
        GLL(gAi0 + ko, dAi0); GLL(gAi1 + ko, dAi1);
        GLL(gBr0 + ko, dBr0); GLL(gBr1 + ko, dBr1);
        GLL(gBi0 + ko, dBi0); GLL(gBi1 + ko, dBi1);
        __syncthreads();
        #pragma unroll
        for (int ks = 0; ks < 4; ++ks) {
            int kc = ks * 2 + half;
            int ao = aoffBase + ((kc ^ (am & 7)) * 8);
            short8 ar = lds8(sAr + ao);
            short8 ai = lds8(sAi + ao);
            short8 an = neg8(ai);
            int bo = boffBase + ((kc ^ (bn & 7)) * 8);
            short8 br = lds8(sBr + bo), bi = lds8(sBi + bo);
            accr = __builtin_amdgcn_mfma_f32_32x32x16_bf16(ar, br, accr, 0, 0, 0);
            accr = __builtin_amdgcn_mfma_f32_32x32x16_bf16(an, bi, accr, 0, 0, 0);
            acci = __builtin_amdgcn_mfma_f32_32x32x16_bf16(ar, bi, acci, 0, 0, 0);
            acci = __builtin_amdgcn_mfma_f32_32x32x16_bf16(ai, br, acci, 0, 0, 0);
        }
    }

    int col = n0 + nw * 32 + l31;
    float bre = (ksl == 0) ? b2r[(size_t)e * ND + col] : 0.0f;
    float bie = (ksl == 0) ? b2i[(size_t)e * ND + col] : 0.0f;
    #pragma unroll
    for (int reg = 0; reg < 16; ++reg) {
        int row = (reg & 3) + 8 * (reg >> 2) + 4 * half;
        int tix = mw * 32 + row;
        if (mbase + tix >= n) continue;
        int tok = toks[tix];
        float gw = gate_w[tok];
        atomicAdd(&out[(size_t)tok * ND + col], (accr[reg] + bre) * gw);
        atomicAdd(&out[(size_t)NT * ND + (size_t)tok * ND + col], (acci[reg] + bie) * gw);
    }
}

extern "C" void kernel_launch(void* const* d_in, const int* in_sizes, int n_in,
                              void* d_out, int out_size, void* d_ws, size_t ws_size,
                              hipStream_t stream) {
    const float* xr   = (const float*)d_in[0];
    const float* xi   = (const float*)d_in[1];
    const float* gW   = (const float*)d_in[2];
    const float* gb   = (const float*)d_in[3];
    const float* W1r  = (const float*)d_in[4];
    const float* W1i  = (const float*)d_in[5];
    const float* b1r  = (const float*)d_in[6];
    const float* b1i  = (const float*)d_in[7];
    const float* modb = (const float*)d_in[8];
    const float* W2r  = (const float*)d_in[9];
    const float* W2i  = (const float*)d_in[10];
    const float* b2r  = (const float*)d_in[11];
    const float* b2i  = (const float*)d_in[12];
    float* out = (float*)d_out;

    char* ws = (char*)d_ws;
    int*   counts   = (int*)ws;                              // 256 B
    float* gate_w   = (float*)(ws + 256);                    // NT*4
    int*   tok_list = (int*)(ws + 256 + 8192);               // NE*NT*4
    size_t off = 256 + 8192 + (size_t)NE * NT * 4;
    unsigned short* xbr  = (unsigned short*)(ws + off); off += (size_t)NT * ND * 2;
    unsigned short* xbi  = (unsigned short*)(ws + off); off += (size_t)NT * ND * 2;
    unsigned short* w1tr = (unsigned short*)(ws + off); off += (size_t)NE * ND * NH * 2;
    unsigned short* w1ti = (unsigned short*)(ws + off); off += (size_t)NE * ND * NH * 2;
    unsigned short* w2tr = (unsigned short*)(ws + off); off += (size_t)NE * ND * NH * 2;
    unsigned short* w2ti = (unsigned short*)(ws + off); off += (size_t)NE * ND * NH * 2;
    unsigned short* h_r  = (unsigned short*)(ws + off); off += (size_t)NT * NH * 2;
    unsigned short* h_i  = (unsigned short*)(ws + off); off += (size_t)NT * NH * 2;

    hipMemsetAsync(counts, 0, 64 * sizeof(int), stream);
    hipMemsetAsync(out, 0, (size_t)out_size * sizeof(float), stream);
    gate_kernel<<<NT, 256, 0, stream>>>(xr, xi, gW, gb, gate_w, counts, tok_list, xbr, xbi);
    transw_kernel<<<dim3(NH / 64, ND / 64, NE), 256, 0, stream>>>(W1r, w1tr, W1i, w1ti, ND, NH);
    transw_kernel<<<dim3(ND / 64, NH / 64, NE), 256, 0, stream>>>(W2r, w2tr, W2i, w2ti, NH, ND);
    moe1_kernel<<<dim3(NH / 128, NT / 64, NE), 256, 0, stream>>>(
        xbr, xbi, w1tr, w1ti, b1r, b1i, modb, counts, tok_list, h_r, h_i);
    moe2_kernel<<<dim3(ND / 64, NT / 64, NE * 4), 256, 0, stream>>>(
        h_r, h_i, w2tr, w2ti, b2r, b2i, counts, tok_list, gate_w, out);
}